// Round 6
// baseline (2210.315 us; speedup 1.0000x reference)
//
#include <hip/hip_runtime.h>

// Weight-stationary LSTM, plain launch + fence-free per-batch-group barriers.
// Grid = 16 bg x 16 ug = 256 blocks x 512 threads (8 waves, 1 block/CU via LDS).
// Cross-block h-state exchanged via agent-scope RELAXED atomics (sc0 sc1 ->
// coherent at LLC, no L2 invalidation ever). Barrier = syncthreads (drains
// vmcnt; write-through stores are LLC-visible) + relaxed fetch_add + spin.
// Weights stay L2/LDS-resident for the whole kernel. c-state in VGPRs.

typedef __bf16 bf16x8 __attribute__((ext_vector_type(8)));
typedef float  f32x4  __attribute__((ext_vector_type(4)));
typedef unsigned long long u64;

#define NMAT 12
#define SLICE_SH 16384                        // shorts per (mat, ug) slice (32 KB)
#define WPACK_SHORTS (NMAT * 16 * SLICE_SH)   // 3,145,728
#define BIAS_OFF_BYTES (WPACK_SHORTS * 2)     // 6,291,456
#define BAR_OFF_BYTES (BIAS_OFF_BYTES + 32768)
#define H_OFF_BYTES (BAR_OFF_BYTES + 4096)
#define HBUF_SHORTS 1048576                   // 4096*256 bf16 = 2 MB

__device__ __host__ inline unsigned short f2bf_u(float f){
  union { float f; unsigned u; } v; v.f = f;
  unsigned u = v.u + 0x7fffu + ((v.u >> 16) & 1u);
  return (unsigned short)(u >> 16);
}
__device__ inline float sigm(float x){ return 1.f / (1.f + __expf(-x)); }
__device__ inline float tanh_(float x){ return 2.f / (1.f + __expf(-2.f * x)) - 1.f; }

// ---- LLC-coherent access helpers (agent scope, relaxed) ----
__device__ inline u64 llc_ld64(const unsigned short* p){
  return __hip_atomic_load((const u64*)p, __ATOMIC_RELAXED, __HIP_MEMORY_SCOPE_AGENT);
}
__device__ inline void llc_st64(unsigned short* p, u64 v){
  __hip_atomic_store((u64*)p, v, __ATOMIC_RELAXED, __HIP_MEMORY_SCOPE_AGENT);
}
__device__ inline bf16x8 llc_ld_frag(const unsigned short* p){
  union { u64 q[2]; bf16x8 v; } u;
  u.q[0] = llc_ld64(p);
  u.q[1] = llc_ld64(p + 4);
  return u.v;
}
__device__ inline void llc_st16(unsigned short* p, unsigned short v){
  __hip_atomic_store(p, v, __ATOMIC_RELAXED, __HIP_MEMORY_SCOPE_AGENT);
}

struct PrepArgs {
  const float* mats[NMAT];
  const float* ba[8];
  const float* bb[8];
  unsigned short* wp;
  float* bias;
  unsigned* bars;
};

// wpack[mi][ug][g][kk][lane][j] <- W[g*256 + ug*16 + (lane&15)][kk*32 + (lane>>4)*8 + j]
__global__ void prep_kernel(PrepArgs a){
  unsigned i = blockIdx.x * 256u + threadIdx.x;
  if (i < (unsigned)WPACK_SHORTS) {
    unsigned mi = i >> 18;
    unsigned ug = (i >> 14) & 15u;
    unsigned g  = (i >> 12) & 3u;
    unsigned kk = (i >> 9) & 7u;
    unsigned l  = (i >> 3) & 63u;
    unsigned j  = i & 7u;
    unsigned src = (g * 256u + ug * 16u + (l & 15u)) * 256u + kk * 32u + (l >> 4) * 8u + j;
    a.wp[i] = f2bf_u(a.mats[mi][src]);
  } else if (i < (unsigned)WPACK_SHORTS + 8192u) {
    unsigned e = i - (unsigned)WPACK_SHORTS;
    unsigned cell = e >> 10, n = e & 1023u;
    a.bias[e] = a.ba[cell][n] + a.bb[cell][n];
  } else if (i < (unsigned)WPACK_SHORTS + 8192u + 1024u) {
    a.bars[i - (unsigned)WPACK_SHORTS - 8192u] = 0u;  // zero barrier state
  }
}

struct MainArgs {
  const float* x;
  const float* encWih0;
  const float* decWih0;
  const float* headW;
  const float* headB;
  const float* confW;
  const float* confB;
  const unsigned short* wpack;
  const float* bias;
  unsigned* bars;
  unsigned short* hb;   // 6 h-buffers: hp0[2], hp1[2], henc0, henc1
  float* out;
};

// Fence-free 16-block barrier. All cross-block data moves via sc0/sc1
// (LLC-coherent) accesses, so no L2 writeback/invalidate is needed.
// __syncthreads() drains each wave's vmcnt (write-through stores are at LLC
// once vmcnt retires). cnt is cumulative; barrier #phase done at 16*phase.
__device__ inline void bg_barrier(unsigned* cnt, unsigned* gen, unsigned phase){
  __syncthreads();
  if (threadIdx.x == 0){
    unsigned arrived = __hip_atomic_fetch_add(cnt, 1u, __ATOMIC_RELAXED,
                                              __HIP_MEMORY_SCOPE_AGENT) + 1u;
    if (arrived == phase * 16u){
      __hip_atomic_store(gen, phase, __ATOMIC_RELAXED, __HIP_MEMORY_SCOPE_AGENT);
    } else {
      unsigned spins = 0;
      while (__hip_atomic_load(gen, __ATOMIC_RELAXED, __HIP_MEMORY_SCOPE_AGENT) < phase){
        __builtin_amdgcn_s_sleep(1);
        if (++spins > (1u << 24)) break;   // failsafe against hard hang
      }
    }
    asm volatile("" ::: "memory");         // compiler fence only
  }
  __syncthreads();
}

// A-frags from global h (bf16 [4096][256]) via LLC loads; B-frags from LDS.
// Wave owns 32 batch rows (mt 0..1).
__device__ inline void gemm_k256(f32x4 acc[2][4],
                                 const unsigned short* __restrict__ hbuf,
                                 int wrow0,
                                 const unsigned short* __restrict__ wl,
                                 int lane){
  const int lr = lane & 15, lg = lane >> 4;
  #pragma unroll
  for (int kp = 0; kp < 4; ++kp){
    bf16x8 A2[2][2], B2[4][2];
    #pragma unroll
    for (int mt = 0; mt < 2; ++mt){
      const unsigned short* rp = hbuf + (size_t)(wrow0 + mt * 16 + lr) * 256 + kp * 64 + lg * 8;
      A2[mt][0] = llc_ld_frag(rp);
      A2[mt][1] = llc_ld_frag(rp + 32);
    }
    #pragma unroll
    for (int gt = 0; gt < 4; ++gt){
      #pragma unroll
      for (int q = 0; q < 2; ++q)
        B2[gt][q] = *reinterpret_cast<const bf16x8*>(wl + ((size_t)(gt * 8 + kp * 2 + q) * 64 + lane) * 8);
    }
    #pragma unroll
    for (int mt = 0; mt < 2; ++mt)
      #pragma unroll
      for (int gt = 0; gt < 4; ++gt){
        f32x4 c = __builtin_amdgcn_mfma_f32_16x16x32_bf16(A2[mt][0], B2[gt][0], acc[mt][gt], 0, 0, 0);
        acc[mt][gt] = __builtin_amdgcn_mfma_f32_16x16x32_bf16(A2[mt][1], B2[gt][1], c, 0, 0, 0);
      }
  }
}

__device__ inline void cell_upd(f32x4 acc[2][4], float cst[2][4],
                                unsigned short* __restrict__ hbuf,
                                int wrow0, int U0, int lane){
  const int lr = lane & 15, lg = lane >> 4;
  #pragma unroll
  for (int mt = 0; mt < 2; ++mt){
    #pragma unroll
    for (int r = 0; r < 4; ++r){
      const float gi = acc[mt][0][r], gf = acc[mt][1][r];
      const float gg = acc[mt][2][r], go = acc[mt][3][r];
      float c = sigm(gf) * cst[mt][r] + sigm(gi) * tanh_(gg);
      cst[mt][r] = c;
      llc_st16(&hbuf[(size_t)(wrow0 + mt * 16 + lg * 4 + r) * 256 + U0 + lr],
               f2bf_u(sigm(go) * tanh_(c)));
    }
  }
}

__device__ inline void init_bias(f32x4 acc[2][4], const float* __restrict__ b, int U0, int lr){
  #pragma unroll
  for (int gt = 0; gt < 4; ++gt){
    const float bb = b[gt * 256 + U0 + lr];
    #pragma unroll
    for (int mt = 0; mt < 2; ++mt) acc[mt][gt] = (f32x4){bb, bb, bb, bb};
  }
}

__global__ __launch_bounds__(512, 1) void lstm_main(MainArgs a){
  __shared__ unsigned short wlds[3][SLICE_SH];  // 96 KB
  __shared__ float pin[256][2];
  __shared__ float hw[512];
  __shared__ float cw[768];

  const int tid = threadIdx.x, wave = tid >> 6, lane = tid & 63;
  const int lr = lane & 15, lg = lane >> 4;
  const int xcd = blockIdx.x & 7, idx = blockIdx.x >> 3;
  const int bg = xcd * 2 + (idx >> 4), ug = idx & 15;
  const int B0 = bg * 256, U0 = ug * 16;
  const int wrow0 = B0 + wave * 32;   // wave owns 32 batch rows

  unsigned* bcnt = a.bars + bg * 32;
  unsigned* bgen = bcnt + 1;
  unsigned phase = 0;

  unsigned short* hp0[2] = { a.hb,                   a.hb + HBUF_SHORTS };
  unsigned short* hp1[2] = { a.hb + 2 * HBUF_SHORTS, a.hb + 3 * HBUF_SHORTS };
  unsigned short* henc0  =   a.hb + 4 * HBUF_SHORTS;
  unsigned short* henc1  =   a.hb + 5 * HBUF_SHORTS;

  // ---- prologue: zero h(-1) slices (LLC stores), stage weights, conf W ----
  if (tid < 256){
    const size_t o = (size_t)(B0 + tid) * 256 + U0;
    #pragma unroll
    for (int q = 0; q < 4; ++q){
      llc_st64(hp0[0] + o + q * 4, 0ull);
      llc_st64(hp1[0] + o + q * 4, 0ull);
    }
  }
  for (int i = tid; i < 768; i += 512) cw[i] = a.confW[i];
  for (int s = 0; s < 3; ++s){
    const uint4* src = (const uint4*)(a.wpack + (size_t)(s * 16 + ug) * SLICE_SH);
    uint4* dst = (uint4*)wlds[s];
    for (int i = tid; i < 2048; i += 512) dst[i] = src[i];
  }
  bg_barrier(bcnt, bgen, ++phase);

  float c0[2][4] = {}, c1[2][4] = {};
  const float* bias0 = a.bias;
  const float* bias1 = a.bias + 1024;

  // ---------------- encoder, skewed: 51 phases ----------------
  // phase s: L0(t=s) [s<50] and L1(t=s-1) [s>=1].
  // h0(t) in hp0[(t+1)&1]; h1(t) in hp1[(t+1)&1].
  for (int s = 0; s <= 50; ++s){
    if (s < 50){
      f32x4 acc[2][4];
      float4 w4[4];
      init_bias(acc, bias0, U0, lr);
      #pragma unroll
      for (int gt = 0; gt < 4; ++gt)
        w4[gt] = *(const float4*)(a.encWih0 + (size_t)(gt * 256 + U0 + lr) * 4);
      #pragma unroll
      for (int mt = 0; mt < 2; ++mt){
        #pragma unroll
        for (int r = 0; r < 4; ++r){
          const float4 xv = *(const float4*)(a.x + (size_t)(wrow0 + mt * 16 + lg * 4 + r) * 200 + s * 4);
          #pragma unroll
          for (int gt = 0; gt < 4; ++gt)
            acc[mt][gt][r] += xv.x * w4[gt].x + xv.y * w4[gt].y + xv.z * w4[gt].z + xv.w * w4[gt].w;
        }
      }
      gemm_k256(acc, hp0[s & 1], wrow0, wlds[0], lane);   // Whh0 @ h0(s-1)
      cell_upd(acc, c0, hp0[(s + 1) & 1], wrow0, U0, lane);
    }
    if (s >= 1){
      f32x4 acc[2][4];
      init_bias(acc, bias1, U0, lr);
      gemm_k256(acc, hp0[s & 1], wrow0, wlds[1], lane);        // Wih1 @ h0(s-1)
      gemm_k256(acc, hp1[(s - 1) & 1], wrow0, wlds[2], lane);  // Whh1 @ h1(s-2)
      cell_upd(acc, c1, hp1[s & 1], wrow0, U0, lane);
    }
    bg_barrier(bcnt, bgen, ++phase);
  }
  // encoder finals: h0(49) in hp0[0], h1(49) in hp1[0]

  // ---- post-encoder: conf head, save henc + c, stage k=0 weights ----
  {
    if (ug == 0 && tid < 256){
      const int row = B0 + tid;
      float l0 = a.confB[0], l1 = a.confB[1], l2 = a.confB[2];
      for (int ch = 0; ch < 32; ++ch){
        const bf16x8 v = llc_ld_frag(hp1[0] + (size_t)row * 256 + ch * 8);
        #pragma unroll
        for (int j = 0; j < 8; ++j){
          const float f = (float)v[j];
          l0 += f * cw[ch * 8 + j];
          l1 += f * cw[256 + ch * 8 + j];
          l2 += f * cw[512 + ch * 8 + j];
        }
      }
      const float mx = fmaxf(l0, fmaxf(l1, l2));
      const float e0 = __expf(l0 - mx), e1 = __expf(l1 - mx), e2 = __expf(l2 - mx);
      const float inv = 1.f / (e0 + e1 + e2);
      a.out[147456 + (size_t)row * 3 + 0] = e0 * inv;
      a.out[147456 + (size_t)row * 3 + 1] = e1 * inv;
      a.out[147456 + (size_t)row * 3 + 2] = e2 * inv;
    }
    if (tid < 256){
      const size_t o = (size_t)(B0 + tid) * 256 + U0;
      #pragma unroll
      for (int q = 0; q < 4; ++q){
        ((u64*)(henc0 + o))[q] = llc_ld64(hp0[0] + o + q * 4);  // henc block-private
        ((u64*)(henc1 + o))[q] = llc_ld64(hp1[0] + o + q * 4);
      }
      pin[tid][0] = a.x[(size_t)(B0 + tid) * 200 + 196];
      pin[tid][1] = a.x[(size_t)(B0 + tid) * 200 + 197];
    }
    for (int s = 0; s < 3; ++s){
      const int mi = 3 * s + 3;  // mats 3,6,9 for k=0
      const uint4* src = (const uint4*)(a.wpack + (size_t)(mi * 16 + ug) * SLICE_SH);
      uint4* dst = (uint4*)wlds[s];
      for (int i = tid; i < 2048; i += 512) dst[i] = src[i];
    }
    for (int i = tid; i < 512; i += 512) hw[i] = a.headW[i];
    for (int i = tid + 512; i < 512; i += 512) {}  // (no-op, clarity)
    if (tid < 512) { if (tid < 512 && tid >= 0) hw[tid] = a.headW[tid]; }
  }
  float c0s[2][4], c1s[2][4];
  #pragma unroll
  for (int mt = 0; mt < 2; ++mt)
    #pragma unroll
    for (int r = 0; r < 4; ++r){ c0s[mt][r] = c0[mt][r]; c1s[mt][r] = c1[mt][r]; }
  bg_barrier(bcnt, bgen, ++phase);

  // ---------------- decoders: 3 sequential passes, skewed ----------------
  // dec h0(t) in hp0[(t+1)&1], h1(t) in hp1[(t+1)&1]; h(-1) in hp*[0].
  for (int k = 0; k < 3; ++k){
    const float* db0 = a.bias + (size_t)(2 + k) * 1024;
    const float* db1 = a.bias + (size_t)(5 + k) * 1024;
    const float hb0 = a.headB[k * 2], hb1 = a.headB[k * 2 + 1];

    if (k > 0){
      // restore phase: henc -> hp*[0] (own slice, LLC stores), c regs, weights, pin
      if (tid < 256){
        const size_t o = (size_t)(B0 + tid) * 256 + U0;
        #pragma unroll
        for (int q = 0; q < 4; ++q){
          llc_st64(hp0[0] + o + q * 4, ((const u64*)(henc0 + o))[q]);
          llc_st64(hp1[0] + o + q * 4, ((const u64*)(henc1 + o))[q]);
        }
        pin[tid][0] = a.x[(size_t)(B0 + tid) * 200 + 196];
        pin[tid][1] = a.x[(size_t)(B0 + tid) * 200 + 197];
      }
      const int m3[3] = {3 + k, 6 + k, 9 + k};
      for (int s = 0; s < 3; ++s){
        const uint4* src = (const uint4*)(a.wpack + (size_t)(m3[s] * 16 + ug) * SLICE_SH);
        uint4* dst = (uint4*)wlds[s];
        for (int i = tid; i < 2048; i += 512) dst[i] = src[i];
      }
      if (tid < 512) hw[tid] = a.headW[(size_t)k * 512 + tid];
      #pragma unroll
      for (int mt = 0; mt < 2; ++mt)
        #pragma unroll
        for (int r = 0; r < 4; ++r){ c0[mt][r] = c0s[mt][r]; c1[mt][r] = c1s[mt][r]; }
      bg_barrier(bcnt, bgen, ++phase);
    }

    auto do_L0 = [&](int t){
      f32x4 acc[2][4];
      float2 w2[4];
      init_bias(acc, db0, U0, lr);
      #pragma unroll
      for (int gt = 0; gt < 4; ++gt)
        w2[gt] = *(const float2*)(a.decWih0 + (size_t)k * 2048 + (size_t)(gt * 256 + U0 + lr) * 2);
      #pragma unroll
      for (int mt = 0; mt < 2; ++mt){
        #pragma unroll
        for (int r = 0; r < 4; ++r){
          const int li = wave * 32 + mt * 16 + lg * 4 + r;
          const float p0 = pin[li][0], p1 = pin[li][1];
          #pragma unroll
          for (int gt = 0; gt < 4; ++gt)
            acc[mt][gt][r] += p0 * w2[gt].x + p1 * w2[gt].y;
        }
      }
      gemm_k256(acc, hp0[t & 1], wrow0, wlds[0], lane);      // Whh0 @ h0(t-1)
      cell_upd(acc, c0, hp0[(t + 1) & 1], wrow0, U0, lane);
    };
    auto do_L1 = [&](int t){
      f32x4 acc[2][4];
      init_bias(acc, db1, U0, lr);
      gemm_k256(acc, hp0[(t + 1) & 1], wrow0, wlds[1], lane); // Wih1 @ h0(t)
      gemm_k256(acc, hp1[t & 1], wrow0, wlds[2], lane);       // Whh1 @ h1(t-1)
      cell_upd(acc, c1, hp1[(t + 1) & 1], wrow0, U0, lane);
    };
    auto do_pred = [&](int t){  // reads h1(t) = hp1[(t+1)&1]; fills pin; ug0 writes out
      if (tid < 256){
        const int row = B0 + tid;
        float s0 = hb0, s1 = hb1;
        for (int ch = 0; ch < 32; ++ch){
          const bf16x8 v = llc_ld_frag(hp1[(t + 1) & 1] + (size_t)row * 256 + ch * 8);
          #pragma unroll
          for (int j = 0; j < 8; ++j){
            const float f = (float)v[j];
            s0 += f * hw[ch * 8 + j];
            s1 += f * hw[256 + ch * 8 + j];
          }
        }
        pin[tid][0] = s0; pin[tid][1] = s1;
        if (ug == 0){
          const size_t ob = (((size_t)row * 3 + k) * 6 + t) * 2;
          a.out[ob] = s0; a.out[ob + 1] = s1;
        }
      }
    };

    do_L0(0);
    bg_barrier(bcnt, bgen, ++phase);
    do_L1(0);
    bg_barrier(bcnt, bgen, ++phase);
    for (int t = 1; t < 6; ++t){
      do_pred(t - 1);
      __syncthreads();              // pin visible block-locally before L0 reads
      do_L0(t);
      bg_barrier(bcnt, bgen, ++phase);
      do_L1(t);
      bg_barrier(bcnt, bgen, ++phase);
    }
    do_pred(5);
    bg_barrier(bcnt, bgen, ++phase);
  }
}

extern "C" void kernel_launch(void* const* d_in, const int* in_sizes, int n_in,
                              void* d_out, int out_size, void* d_ws, size_t ws_size,
                              hipStream_t stream){
  PrepArgs pa;
  pa.mats[0] = (const float*)d_in[2];   // enc_Whh0
  pa.mats[1] = (const float*)d_in[5];   // enc_Wih1
  pa.mats[2] = (const float*)d_in[6];   // enc_Whh1
  for (int k = 0; k < 3; ++k){
    pa.mats[3 + k] = (const float*)d_in[10] + (size_t)k * 262144;  // dec_Whh0[k]
    pa.mats[6 + k] = (const float*)d_in[13] + (size_t)k * 262144;  // dec_Wih1[k]
    pa.mats[9 + k] = (const float*)d_in[14] + (size_t)k * 262144;  // dec_Whh1[k]
  }
  pa.ba[0] = (const float*)d_in[3];  pa.bb[0] = (const float*)d_in[4];
  pa.ba[1] = (const float*)d_in[7];  pa.bb[1] = (const float*)d_in[8];
  for (int k = 0; k < 3; ++k){
    pa.ba[2 + k] = (const float*)d_in[11] + (size_t)k * 1024;
    pa.bb[2 + k] = (const float*)d_in[12] + (size_t)k * 1024;
    pa.ba[5 + k] = (const float*)d_in[15] + (size_t)k * 1024;
    pa.bb[5 + k] = (const float*)d_in[16] + (size_t)k * 1024;
  }
  pa.wp   = (unsigned short*)d_ws;
  pa.bias = (float*)((char*)d_ws + BIAS_OFF_BYTES);
  pa.bars = (unsigned*)((char*)d_ws + BAR_OFF_BYTES);

  prep_kernel<<<12324, 256, 0, stream>>>(pa);

  MainArgs ma;
  ma.x       = (const float*)d_in[0];
  ma.encWih0 = (const float*)d_in[1];
  ma.decWih0 = (const float*)d_in[9];
  ma.headW   = (const float*)d_in[17];
  ma.headB   = (const float*)d_in[18];
  ma.confW   = (const float*)d_in[19];
  ma.confB   = (const float*)d_in[20];
  ma.wpack   = (const unsigned short*)d_ws;
  ma.bias    = (const float*)((char*)d_ws + BIAS_OFF_BYTES);
  ma.bars    = (unsigned*)((char*)d_ws + BAR_OFF_BYTES);
  ma.hb      = (unsigned short*)((char*)d_ws + H_OFF_BYTES);
  ma.out     = (float*)d_out;

  lstm_main<<<256, 512, 0, stream>>>(ma);
}